// Round 5
// baseline (1790.781 us; speedup 1.0000x reference)
//
#include <hip/hip_runtime.h>
#include <math.h>

#define BATCH 1024
#define TSEQ  2048
#define DIN   5
#define XSTR  6      // xs stride in halves (pad 5->6 for half2 alignment)
#define H     64
#define BT    2      // batch elems per block -> grid 512 = 2 blocks/CU
#define NOUT  128

typedef _Float16 f16x8  __attribute__((ext_vector_type(8)));
typedef _Float16 half2v __attribute__((ext_vector_type(2)));
typedef float    f32x4  __attribute__((ext_vector_type(4)));

#if __has_builtin(__builtin_amdgcn_fdot2)
__device__ __forceinline__ float FDOT2(half2v a, half2v b, float c) {
    return __builtin_amdgcn_fdot2(a, b, c, false);
}
#else
__device__ __forceinline__ float FDOT2(half2v a, half2v b, float c) {
    return fmaf((float)a.x, (float)b.x, fmaf((float)a.y, (float)b.y, c));
}
#endif

#if __has_builtin(__builtin_amdgcn_rcpf)
__device__ __forceinline__ float rcp_fast(float x) { return __builtin_amdgcn_rcpf(x); }
#else
__device__ __forceinline__ float rcp_fast(float x) { return 1.0f / x; }
#endif

__device__ __forceinline__ float sigmoid_fast(float x) {
    return rcp_fast(1.0f + __expf(-x));
}
__device__ __forceinline__ float tanh_fast(float x) {
    return 1.0f - 2.0f * rcp_fast(__expf(2.0f * x) + 1.0f);
}

// Transposed-MFMA LSTM: A = state [y1(64);h2(64)] (m=elem via m&1 broadcast),
// B = weight columns (n = gate-row within wave's 16 h-units). D then delivers
// all 4 gate raws of (hu, e) into one lane's registers -> gate activation and
// c/h update happen IN REGISTERS (no raw LDS round-trip), quad-specialized:
//   quad 0: layer-1 e0, quad 1: layer-1 e1, quad 2: layer-2 e0, quad 3: layer-2 e1.
// State buffer (1 KB) is double-buffered -> ONE barrier per timestep.
__global__ __launch_bounds__(256) __attribute__((amdgpu_waves_per_eu(2, 2)))
void lstm_mfma(const float* __restrict__ x,
               const float* __restrict__ Wih0, const float* __restrict__ Whh0,
               const float* __restrict__ bih0, const float* __restrict__ bhh0,
               const float* __restrict__ Wih1, const float* __restrict__ Whh1,
               const float* __restrict__ bih1, const float* __restrict__ bhh1,
               const float* __restrict__ Wfc,  const float* __restrict__ bfc,
               float* __restrict__ out)
{
    __shared__ alignas(16) _Float16 xs[BT][TSEQ * XSTR];   // 48 KB fp16 input
    __shared__ alignas(16) _Float16 Abuf[2][BT * 128];     // 1 KB x2: state [e][y1(64);h2(64)]
    __shared__ alignas(16) float    h2f[BT][H];            // final h2 for FC

    const int tid = threadIdx.x;
    const int w   = tid >> 6;          // wave id -> h-units [16w, 16w+16)
    const int col = tid & 15;          // n within tile = h-unit offset
    const int qd  = (tid >> 4) & 3;    // quad
    const int hu  = 16 * w + col;      // this lane's G-phase h-unit
    const int e   = qd & 1;            // this lane's G-phase elem
    const int lay = qd >> 1;           // 0 = layer-1, 1 = layer-2
    const int b0  = blockIdx.x * BT;

    // ---------------- prologue: stage x (fp32 -> fp16, stride 5 -> 6) ----------------
    for (int el = 0; el < BT; ++el) {
        const float* xb = x + (size_t)(b0 + el) * TSEQ * DIN;
        for (int idx = tid; idx < TSEQ * DIN; idx += 256) {
            int t = idx / DIN;
            int d = idx - t * DIN;
            xs[el][t * XSTR + d] = (_Float16)xb[idx];
        }
        for (int t = tid; t < TSEQ; t += 256)
            xs[el][t * XSTR + DIN] = (_Float16)0.0f;
    }
    for (int j = tid; j < 2 * BT * 128; j += 256)
        ((_Float16*)Abuf)[j] = (_Float16)0.0f;

    // ---------------- B-fragments: weights, resident in registers ----------------
    // B[k=qd*8+j][n=col], n-tile g = gate g rows {g*64 + hu}.
    f16x8 B1[4][2];   // layer-1: Whh0, K = 64 (ktiles 0,1 over y1)
    f16x8 B2[4][4];   // layer-2: [Wih1 | Whh1], K = 128
    #pragma unroll
    for (int g = 0; g < 4; ++g) {
        const int row = g * 64 + hu;
        #pragma unroll
        for (int kt = 0; kt < 2; ++kt) {
            const float* p = Whh0 + row * H + kt * 32 + qd * 8;
            f16x8 f;
            #pragma unroll
            for (int j = 0; j < 8; ++j) f[j] = (_Float16)p[j];
            B1[g][kt] = f;
        }
        #pragma unroll
        for (int kt = 0; kt < 2; ++kt) {
            const float* p = Wih1 + row * H + kt * 32 + qd * 8;
            f16x8 f;
            #pragma unroll
            for (int j = 0; j < 8; ++j) f[j] = (_Float16)p[j];
            B2[g][kt] = f;
        }
        #pragma unroll
        for (int kt = 0; kt < 2; ++kt) {
            const float* p = Whh1 + row * H + kt * 32 + qd * 8;
            f16x8 f;
            #pragma unroll
            for (int j = 0; j < 8; ++j) f[j] = (_Float16)p[j];
            B2[g][2 + kt] = f;
        }
    }

    // ---------------- G-phase constants (per lane: its hu's 4 gate rows) ----------------
    half2v w0x[4][3];
    float  bias0g[4], bias1g[4];
    #pragma unroll
    for (int g = 0; g < 4; ++g) {
        const int row = g * 64 + hu;
        const float* r = Wih0 + row * DIN;
        w0x[g][0] = half2v{(_Float16)r[0], (_Float16)r[1]};
        w0x[g][1] = half2v{(_Float16)r[2], (_Float16)r[3]};
        w0x[g][2] = half2v{(_Float16)r[4], (_Float16)0.0f};
        bias0g[g] = bih0[row] + bhh0[row];
        bias1g[g] = bih1[row] + bhh1[row];
    }

    float cst = 0.0f;      // c1 (quads 0,1) or c2 (quads 2,3) for (hu, e)
    float h2fin = 0.0f;
    const f32x4 zz = {0.0f, 0.0f, 0.0f, 0.0f};

    __syncthreads();

    // ============ main loop: iter i = layer-1(t=i) + layer-2(t=i-1), ONE barrier ============
    #pragma unroll 1
    for (int i = 0; i <= TSEQ; ++i) {
        // ---- M: A-frags from state buf[(i-1)&1] (broadcast by m&1), 24 mfma ----
        const _Float16* src = Abuf[(i + 1) & 1];   // (i-1)&1 == (i+1)&1
        f16x8 af[4];
        #pragma unroll
        for (int kt = 0; kt < 4; ++kt)
            af[kt] = *(const f16x8*)&src[(col & 1) * 128 + kt * 32 + qd * 8];

        f32x4 d1[4], d2[4];
        #pragma unroll
        for (int g = 0; g < 4; ++g) {
            d1[g] = __builtin_amdgcn_mfma_f32_16x16x32_f16(af[0], B1[g][0], zz, 0, 0, 0);
            d1[g] = __builtin_amdgcn_mfma_f32_16x16x32_f16(af[1], B1[g][1], d1[g], 0, 0, 0);
            d2[g] = __builtin_amdgcn_mfma_f32_16x16x32_f16(af[0], B2[g][0], zz, 0, 0, 0);
            d2[g] = __builtin_amdgcn_mfma_f32_16x16x32_f16(af[1], B2[g][1], d2[g], 0, 0, 0);
            d2[g] = __builtin_amdgcn_mfma_f32_16x16x32_f16(af[2], B2[g][2], d2[g], 0, 0, 0);
            d2[g] = __builtin_amdgcn_mfma_f32_16x16x32_f16(af[3], B2[g][3], d2[g], 0, 0, 0);
        }
        // D row = qd*4 + reg, elem(row) = row&1 -> this lane's (e=qd&1) value is reg e.

        _Float16* wbuf = Abuf[i & 1];
        if (lay == 0) {
            if (i < TSEQ) {   // layer-1 update for t = i, elem e
                const half2v* xv = (const half2v*)(xs[e] + i * XSTR);
                half2v xa = xv[0], xb = xv[1], xc = xv[2];
                float p0 = FDOT2(xc, w0x[0][2], FDOT2(xb, w0x[0][1], FDOT2(xa, w0x[0][0], bias0g[0])));
                float p1 = FDOT2(xc, w0x[1][2], FDOT2(xb, w0x[1][1], FDOT2(xa, w0x[1][0], bias0g[1])));
                float p2 = FDOT2(xc, w0x[2][2], FDOT2(xb, w0x[2][1], FDOT2(xa, w0x[2][0], bias0g[2])));
                float p3 = FDOT2(xc, w0x[3][2], FDOT2(xb, w0x[3][1], FDOT2(xa, w0x[3][0], bias0g[3])));
                p0 += e ? d1[0].y : d1[0].x;
                p1 += e ? d1[1].y : d1[1].x;
                p2 += e ? d1[2].y : d1[2].x;
                p3 += e ? d1[3].y : d1[3].x;
                float iv = sigmoid_fast(p0);
                float fv = sigmoid_fast(p1);
                float gv = tanh_fast(p2);
                float ov = sigmoid_fast(p3);
                cst = fmaf(fv, cst, iv * gv);
                wbuf[e * 128 + hu] = (_Float16)(ov * tanh_fast(cst));
            }
        } else {
            if (i > 0) {      // layer-2 update for t = i-1, elem e
                float q0 = bias1g[0] + (e ? d2[0].y : d2[0].x);
                float q1 = bias1g[1] + (e ? d2[1].y : d2[1].x);
                float q2 = bias1g[2] + (e ? d2[2].y : d2[2].x);
                float q3 = bias1g[3] + (e ? d2[3].y : d2[3].x);
                float iv = sigmoid_fast(q0);
                float fv = sigmoid_fast(q1);
                float gv = tanh_fast(q2);
                float ov = sigmoid_fast(q3);
                cst = fmaf(fv, cst, iv * gv);
                h2fin = ov * tanh_fast(cst);
                wbuf[e * 128 + 64 + hu] = (_Float16)h2fin;
            }
        }
        __syncthreads();   // buf[i&1] ready for iter i+1; also fences WAR on buf[(i-1)&1]
    }

    // ---------------- epilogue: out = relu(h2(T-1) @ Wfc^T + bfc) ----------------
    if (lay == 1) h2f[e][hu] = h2fin;   // h2 lives in quads 2,3
    __syncthreads();
    {
        const int eo = tid >> 7;         // 0 or 1
        const int o  = tid & (NOUT - 1); // 0..127
        const float4* wr = (const float4*)(Wfc + o * H);
        const float*  hv = h2f[eo];
        float s0 = 0.0f, s1 = 0.0f, s2 = 0.0f, s3 = 0.0f;
        #pragma unroll
        for (int k = 0; k < H / 4; ++k) {
            float4 wv = wr[k];
            s0 = fmaf(wv.x, hv[4 * k + 0], s0);
            s1 = fmaf(wv.y, hv[4 * k + 1], s1);
            s2 = fmaf(wv.z, hv[4 * k + 2], s2);
            s3 = fmaf(wv.w, hv[4 * k + 3], s3);
        }
        float acc = bfc[o] + (s0 + s1) + (s2 + s3);
        out[(size_t)(b0 + eo) * NOUT + o] = fmaxf(acc, 0.0f);
    }
}

extern "C" void kernel_launch(void* const* d_in, const int* in_sizes, int n_in,
                              void* d_out, int out_size, void* d_ws, size_t ws_size,
                              hipStream_t stream) {
    const float* x    = (const float*)d_in[0];
    const float* Wih0 = (const float*)d_in[1];
    const float* Whh0 = (const float*)d_in[2];
    const float* bih0 = (const float*)d_in[3];
    const float* bhh0 = (const float*)d_in[4];
    const float* Wih1 = (const float*)d_in[5];
    const float* Whh1 = (const float*)d_in[6];
    const float* bih1 = (const float*)d_in[7];
    const float* bhh1 = (const float*)d_in[8];
    const float* Wfc  = (const float*)d_in[9];
    const float* bfc  = (const float*)d_in[10];
    float* out = (float*)d_out;

    lstm_mfma<<<dim3(BATCH / BT), dim3(256), 0, stream>>>(
        x, Wih0, Whh0, bih0, bhh0, Wih1, Whh1, bih1, bhh1, Wfc, bfc, out);
}